// Round 8
// baseline (398.832 us; speedup 1.0000x reference)
//
#include <hip/hip_runtime.h>

#define D 128
#define NH 8
#define CH 16
#define NEG 0.2f
#define BN_EPS 1e-5f
#define MAXDEG 32
#define NSLICE 32
#define WROWS 144            // 128 weight cols + 16 score cols

typedef unsigned int uint;
typedef unsigned short ushort;
typedef __attribute__((ext_vector_type(8))) short bfrag;
typedef __attribute__((ext_vector_type(4))) float ffrag;

__device__ __forceinline__ float bf_lo(uint u){ return __uint_as_float(u << 16); }
__device__ __forceinline__ float bf_hi(uint u){ return __uint_as_float(u & 0xffff0000u); }
__device__ __forceinline__ float bf2f(ushort s){ return __uint_as_float(((uint)s) << 16); }
__device__ __forceinline__ ushort f2b(float f){
  uint u = __float_as_uint(f);
  u += 0x7fffu + ((u >> 16) & 1u);      // round-to-nearest-even
  return (ushort)(u >> 16);
}

// ---------------- CSR build: row-major slotted scatter (col pre-zeroed) ----------------
__global__ void k_scatter(const int* __restrict__ ei, int* __restrict__ deg,
                          int* __restrict__ col, int E){
  int e = blockIdx.x*blockDim.x + threadIdx.x;
  if (e < E){
    int d = ei[E + e];
    int pos = atomicAdd(&deg[d], 1);
    if (pos < MAXDEG) col[(size_t)d*MAXDEG + pos] = ei[e];
  }
}

// ---------------- fused setup: init | gbound | wprep | wsc ----------------
__global__ void k_setup(const float* __restrict__ x, const float* __restrict__ Wp,
                        const float* __restrict__ bp, ushort* __restrict__ h,
                        const int* __restrict__ batch, int* __restrict__ gs,
                        const float* __restrict__ Wg, const float* __restrict__ asrc,
                        const float* __restrict__ adst, ushort* __restrict__ WtB,
                        int n, int G, int WTOT, int bInit, int bGb, int bWp){
  int bid = blockIdx.x;
  int t = threadIdx.x;
  if (bid < bInit){
    int i = bid*256 + t;
    if (i >= n*32) return;
    int nid = i >> 5, d4 = (i & 31)*4;
    const float* xr = x + nid*16;
    float s[4] = { bp[d4], bp[d4+1], bp[d4+2], bp[d4+3] };
#pragma unroll
    for (int k = 0; k < 16; k++){
      float xv = xr[k];
      const float* wr = Wp + k*D + d4;
      s[0] += xv*wr[0]; s[1] += xv*wr[1]; s[2] += xv*wr[2]; s[3] += xv*wr[3];
    }
    uint2 o;
    o.x = ((uint)f2b(fmaxf(s[0],0.f))) | (((uint)f2b(fmaxf(s[1],0.f))) << 16);
    o.y = ((uint)f2b(fmaxf(s[2],0.f))) | (((uint)f2b(fmaxf(s[3],0.f))) << 16);
    *(uint2*)(h + (size_t)nid*D + d4) = o;
  } else if (bid < bInit + bGb){
    int i = (bid - bInit)*256 + t;
    if (i >= n) return;
    int b = batch[i];
    int bpv = (i == 0) ? -1 : batch[i-1];
    for (int g = bpv + 1; g <= b; g++) gs[g] = i;
    if (i == n-1) for (int g = b + 1; g <= G; g++) gs[g] = n;
  } else if (bid < bInit + bGb + bWp){
    int i = (bid - bInit - bGb)*256 + t;
    if (i >= WTOT) return;
    int l = i >> 14, r = i & 16383, nn = r >> 7, kk = r & 127;
    WtB[(size_t)l*WROWS*D + nn*D + kk] = f2b(Wg[(size_t)l*16384 + kk*128 + nn]);
  } else {
    int i = (bid - bInit - bGb - bWp)*256 + t;
    int wscTot = (WTOT >> 14)*16*128;     // L*16*128
    if (i >= wscTot) return;
    int l = i >> 11, r = i & 2047, j = r >> 7, k = r & 127;
    const float* wrow = Wg + (size_t)l*16384 + k*128;
    float s = 0.f;
    if (j < 8){
      const float* av = asrc + l*128 + j*16;
#pragma unroll
      for (int c = 0; c < 16; c++) s += wrow[j*16 + c] * av[c];
    } else {
      const float* av = adst + l*128 + (j - 8)*16;
#pragma unroll
      for (int c = 0; c < 16; c++) s += wrow[(j - 8)*16 + c] * av[c];
    }
    WtB[(size_t)l*WROWS*D + (128 + j)*D + k] = f2b(s);
  }
}

// ---------------- MFMA bf16 GEMM 256x144: A loads hoisted above the barrier ------------
// Raw A-tile global loads are issued FIRST so their ~900cy HBM latency hides under
// B staging + sS/sB compute + barrier (loads cannot be compiler-hoisted across
// __syncthreads). Only the BN+ReLU register conversion remains after the barrier.
__global__ __launch_bounds__(512) void k_gemm(const ushort* __restrict__ hin,
                                              const ushort* __restrict__ WtB,
                                              ushort* __restrict__ xh,
                                              float* __restrict__ sc2,
                                              const float* __restrict__ bnsum,
                                              const float* __restrict__ gamma,
                                              const float* __restrict__ beta,
                                              int n, int first){
  __shared__ __align__(16) ushort wL[WROWS*136];   // 144 rows x (128+8 pad) = 39168 B
  __shared__ float sS[128], sB[128];
  int t = threadIdx.x;
  int wid = t >> 6, lane = t & 63, l15 = lane & 15, quad = lane >> 4;
  int n0 = blockIdx.x * 256;
  int rbase = wid*32;                  // wave-private row base (0..224)

  // ---- issue raw A loads first (HBM latency overlaps everything below) ----
  bfrag araw[2][4];
#pragma unroll
  for (int mt = 0; mt < 2; mt++){
    int row = n0 + rbase + mt*16 + l15;
#pragma unroll
    for (int ks = 0; ks < 4; ks++){
      bfrag v = (bfrag){0,0,0,0,0,0,0,0};
      if (row < n) v = *(const bfrag*)(hin + (size_t)row*D + ks*32 + quad*8);
      araw[mt][ks] = v;
    }
  }

  if (t < 128){
    float sc, sh;
    if (first){ sc = 1.f; sh = 0.f; }
    else {
      float s = 0.f, s2 = 0.f;
#pragma unroll 8
      for (int sl = 0; sl < NSLICE; sl++){
        s  += bnsum[sl*256 + t];
        s2 += bnsum[sl*256 + 128 + t];
      }
      float invn = 1.0f / (float)n;
      float mu = s * invn;
      float var = s2 * invn - mu*mu;
      sc = gamma[t] * rsqrtf(var + BN_EPS);
      sh = beta[t] - mu*sc;
    }
    sS[t] = sc; sB[t] = sh;
  }
  // stage B: 144 rows x 16 uint4 = 2304 uint4 over 512 threads
#pragma unroll
  for (int i = 0; i < 5; i++){
    int u = t + i*512;
    if (u < WROWS*16){
      int r = u >> 4, c8 = u & 15;
      *(uint4*)(wL + r*136 + c8*8) = *(const uint4*)(WtB + (size_t)r*D + c8*8);
    }
  }
  __syncthreads();   // the only barrier

  // BN+ReLU conversion in registers (A data already arrived)
  bfrag a[2][4];
#pragma unroll
  for (int mt = 0; mt < 2; mt++){
#pragma unroll
    for (int ks = 0; ks < 4; ks++){
      union { bfrag b; ushort us[8]; } in, ov;
      in.b = araw[mt][ks];
      int kb = ks*32 + quad*8;
#pragma unroll
      for (int j = 0; j < 8; j++){
        float f = bf2f(in.us[j])*sS[kb + j] + sB[kb + j];
        ov.us[j] = f2b(f > 0.f ? f : 0.f);
      }
      a[mt][ks] = ov.b;
    }
  }

  ffrag acc[2][9];
#pragma unroll
  for (int mt = 0; mt < 2; mt++)
#pragma unroll
    for (int nt = 0; nt < 9; nt++) acc[mt][nt] = (ffrag){0.f,0.f,0.f,0.f};

  // MFMA with LDS-resident B; nt==8 is the score-column tile
#pragma unroll
  for (int nt = 0; nt < 9; nt++){
#pragma unroll
    for (int ks = 0; ks < 4; ks++){
      bfrag b = *(const bfrag*)(wL + (nt*16 + l15)*136 + ks*32 + quad*8);
      acc[0][nt] = __builtin_amdgcn_mfma_f32_16x16x32_bf16(a[0][ks], b, acc[0][nt], 0, 0, 0);
      acc[1][nt] = __builtin_amdgcn_mfma_f32_16x16x32_bf16(a[1][ks], b, acc[1][nt], 0, 0, 0);
    }
  }

  // epilogue: direct stores, no LDS. C mapping: row = rbase+mt*16+quad*4+r, col = nt*16+l15.
#pragma unroll
  for (int mt = 0; mt < 2; mt++)
#pragma unroll
    for (int r = 0; r < 4; r++){
      int grow = n0 + rbase + mt*16 + quad*4 + r;
      if (grow < n){
        sc2[(size_t)grow*16 + l15] = acc[mt][8][r];
        ushort* xr = xh + (size_t)grow*D + l15;
#pragma unroll
        for (int nt = 0; nt < 8; nt++)
          xr[nt*16] = f2b(acc[mt][nt][r]);
      }
    }
}

// ---------------- wave-per-2-nodes aggregation (R2 measured-best, verbatim) ------------
__global__ __launch_bounds__(512) void k_agg(const uint* __restrict__ xh32,
                                             const float* __restrict__ sc2,
                                             const int* __restrict__ deg,
                                             const int* __restrict__ col,
                                             const float* __restrict__ bg,
                                             ushort* __restrict__ hout,
                                             float* __restrict__ bnsum, int n){
  int wv = threadIdx.x >> 6;
  int l  = threadIdx.x & 63;
  int hs = l & 7;
  int jc = l >> 3;
  int n0 = (blockIdx.x*8 + wv)*2;
  int n1 = n0 + 1;
  bool vA = n0 < n, vB = n1 < n;
  int na = vA ? n0 : 0, nb = vB ? n1 : 0;

  float bnS0=0.f, bnS1=0.f, bnQ0=0.f, bnQ1=0.f;
  float b0 = bg[2*l], b1 = bg[2*l + 1];

  // ---- prefetch phase: everything for chunk 1 of both nodes ----
  int cntA = deg[na]; if (cntA > MAXDEG) cntA = MAXDEG; if (!vA) cntA = 0;
  int cntB = deg[nb]; if (cntB > MAXDEG) cntB = MAXDEG; if (!vB) cntB = 0;
  const int* cbA = col + na*MAXDEG;
  const int* cbB = col + nb*MAXDEG;
  int idxA[8], idxB[8];
#pragma unroll
  for (int j = 0; j < 8; j++){ idxA[j] = cbA[j]; idxB[j] = cbB[j]; }
  int myA = cbA[jc], myB = cbB[jc];          // per-lane slot id
  float asA = sc2[na*16 + hs],     asB = sc2[nb*16 + hs];
  float adA = sc2[na*16 + 8 + hs], adB = sc2[nb*16 + 8 + hs];
  uint selfA = xh32[na*64 + l],    selfB = xh32[nb*64 + l];
  float avA = sc2[myA*16 + hs],    avB = sc2[myB*16 + hs];
  uint gA[8], gB[8];
#pragma unroll
  for (int j = 0; j < 8; j++){ gA[j] = xh32[idxA[j]*64 + l]; gB[j] = xh32[idxB[j]*64 + l]; }

  // ---- interleaved chunk-1 compute ----
  int ccA = cntA < 8 ? cntA : 8;
  int ccB = cntB < 8 ? cntB : 8;
  float e0A = asA + adA; e0A = e0A > 0.f ? e0A : NEG*e0A;
  float e0B = asB + adB; e0B = e0B > 0.f ? e0B : NEG*e0B;
  float mA = e0A, dnmA = 1.f, accA0 = bf_lo(selfA), accA1 = bf_hi(selfA);
  float mB = e0B, dnmB = 1.f, accB0 = bf_lo(selfB), accB1 = bf_hi(selfB);

  float eA = -1e30f, eB = -1e30f;
  if (jc < ccA){ float ee = avA + adA; eA = ee > 0.f ? ee : NEG*ee; }
  if (jc < ccB){ float ee = avB + adB; eB = ee > 0.f ? ee : NEG*ee; }
  float mcA = eA, mcB = eB;
  mcA = fmaxf(mcA, __shfl_xor(mcA, 8));  mcB = fmaxf(mcB, __shfl_xor(mcB, 8));
  mcA = fmaxf(mcA, __shfl_xor(mcA, 16)); mcB = fmaxf(mcB, __shfl_xor(mcB, 16));
  mcA = fmaxf(mcA, __shfl_xor(mcA, 32)); mcB = fmaxf(mcB, __shfl_xor(mcB, 32));
  float mnA = fmaxf(mA, mcA),            mnB = fmaxf(mB, mcB);
  float rscA = __expf(mA - mnA),         rscB = __expf(mB - mnB);
  float wA = (jc < ccA) ? __expf(eA - mnA) : 0.f;
  float wB = (jc < ccB) ? __expf(eB - mnB) : 0.f;
  float wsA = wA, wsB = wB;
  wsA += __shfl_xor(wsA, 8);  wsB += __shfl_xor(wsB, 8);
  wsA += __shfl_xor(wsA, 16); wsB += __shfl_xor(wsB, 16);
  wsA += __shfl_xor(wsA, 32); wsB += __shfl_xor(wsB, 32);
  dnmA = dnmA*rscA + wsA;                dnmB = dnmB*rscB + wsB;
  mA = mnA;                              mB = mnB;
  float rcA = __shfl(rscA, jc),          rcB = __shfl(rscB, jc);
  accA0 *= rcA; accA1 *= rcA;            accB0 *= rcB; accB1 *= rcB;
#pragma unroll
  for (int jj = 0; jj < 8; jj++){
    float wjA = __shfl(wA, jj*8 + jc);
    float wjB = __shfl(wB, jj*8 + jc);
    accA0 += wjA * bf_lo(gA[jj]); accA1 += wjA * bf_hi(gA[jj]);
    accB0 += wjB * bf_lo(gB[jj]); accB1 += wjB * bf_hi(gB[jj]);
  }

  // ---- rare serial remainders (deg > 8), per node ----
  for (int c0 = 8; c0 < cntA; c0 += 8){
    int cc2 = cntA - c0; if (cc2 > 8) cc2 = 8;
    int my2 = cbA[c0 + jc];
    float av2 = sc2[my2*16 + hs];
    uint g2[8];
#pragma unroll
    for (int jj = 0; jj < 8; jj++) g2[jj] = xh32[cbA[c0 + jj]*64 + l];
    float e2 = -1e30f;
    if (jc < cc2){ float ee = av2 + adA; e2 = ee > 0.f ? ee : NEG*ee; }
    float mc2 = e2;
    mc2 = fmaxf(mc2, __shfl_xor(mc2, 8));
    mc2 = fmaxf(mc2, __shfl_xor(mc2, 16));
    mc2 = fmaxf(mc2, __shfl_xor(mc2, 32));
    float mn2 = fmaxf(mA, mc2);
    float rsc2 = __expf(mA - mn2);
    float w2 = (jc < cc2) ? __expf(e2 - mn2) : 0.f;
    float ws2 = w2;
    ws2 += __shfl_xor(ws2, 8);
    ws2 += __shfl_xor(ws2, 16);
    ws2 += __shfl_xor(ws2, 32);
    dnmA = dnmA*rsc2 + ws2; mA = mn2;
    float rc2 = __shfl(rsc2, jc);
    accA0 *= rc2; accA1 *= rc2;
#pragma unroll
    for (int jj = 0; jj < 8; jj++){
      float wj = __shfl(w2, jj*8 + jc);
      accA0 += wj * bf_lo(g2[jj]); accA1 += wj * bf_hi(g2[jj]);
    }
  }
  for (int c0 = 8; c0 < cntB; c0 += 8){
    int cc2 = cntB - c0; if (cc2 > 8) cc2 = 8;
    int my2 = cbB[c0 + jc];
    float av2 = sc2[my2*16 + hs];
    uint g2[8];
#pragma unroll
    for (int jj = 0; jj < 8; jj++) g2[jj] = xh32[cbB[c0 + jj]*64 + l];
    float e2 = -1e30f;
    if (jc < cc2){ float ee = av2 + adB; e2 = ee > 0.f ? ee : NEG*ee; }
    float mc2 = e2;
    mc2 = fmaxf(mc2, __shfl_xor(mc2, 8));
    mc2 = fmaxf(mc2, __shfl_xor(mc2, 16));
    mc2 = fmaxf(mc2, __shfl_xor(mc2, 32));
    float mn2 = fmaxf(mB, mc2);
    float rsc2 = __expf(mB - mn2);
    float w2 = (jc < cc2) ? __expf(e2 - mn2) : 0.f;
    float ws2 = w2;
    ws2 += __shfl_xor(ws2, 8);
    ws2 += __shfl_xor(ws2, 16);
    ws2 += __shfl_xor(ws2, 32);
    dnmB = dnmB*rsc2 + ws2; mB = mn2;
    float rc2 = __shfl(rsc2, jc);
    accB0 *= rc2; accB1 *= rc2;
#pragma unroll
    for (int jj = 0; jj < 8; jj++){
      float wj = __shfl(w2, jj*8 + jc);
      accB0 += wj * bf_lo(g2[jj]); accB1 += wj * bf_hi(g2[jj]);
    }
  }

  // ---- finalize both nodes ----
  float dfA = __shfl(dnmA, jc), dfB = __shfl(dnmB, jc);
  float invA = 1.0f / dfA,      invB = 1.0f / dfB;
  float oA0 = accA0*invA + b0,  oA1 = accA1*invA + b1;
  float oB0 = accB0*invB + b0,  oB1 = accB1*invB + b1;
  if (vA){
    uint p = ((uint)f2b(oA0)) | (((uint)f2b(oA1)) << 16);
    ((uint*)hout)[n0*64 + l] = p;
    bnS0 += oA0; bnS1 += oA1; bnQ0 += oA0*oA0; bnQ1 += oA1*oA1;
  }
  if (vB){
    uint p = ((uint)f2b(oB0)) | (((uint)f2b(oB1)) << 16);
    ((uint*)hout)[n1*64 + l] = p;
    bnS0 += oB0; bnS1 += oB1; bnQ0 += oB0*oB0; bnQ1 += oB1*oB1;
  }

  // ---- block BN reduction ----
  __shared__ float red[8][64][4];
  red[wv][l][0] = bnS0; red[wv][l][1] = bnS1; red[wv][l][2] = bnQ0; red[wv][l][3] = bnQ1;
  __syncthreads();
  if (wv == 0){
    float t0 = 0.f, t1 = 0.f, t2 = 0.f, t3 = 0.f;
#pragma unroll
    for (int k = 0; k < 8; k++){
      t0 += red[k][l][0]; t1 += red[k][l][1];
      t2 += red[k][l][2]; t3 += red[k][l][3];
    }
    float* bs = bnsum + (blockIdx.x & (NSLICE - 1))*256;
    atomicAdd(&bs[2*l],       t0);
    atomicAdd(&bs[2*l + 1],   t1);
    atomicAdd(&bs[128 + 2*l], t2);
    atomicAdd(&bs[129 + 2*l], t3);
  }
}

// ---------------- fused pool (BN+ReLU) + output heads ----------------
__global__ __launch_bounds__(128) void k_poolheads(const ushort* __restrict__ h,
                                                   const int* __restrict__ gs,
                                                   const float* __restrict__ bnsum,
                                                   const float* __restrict__ gamma,
                                                   const float* __restrict__ beta,
                                                   const float* __restrict__ hW1,
                                                   const float* __restrict__ hb1,
                                                   const float* __restrict__ hW2,
                                                   const float* __restrict__ hb2,
                                                   float* __restrict__ out, int n){
  int g = blockIdx.x;
  int t = threadIdx.x;
  __shared__ float sp[128];
  int st = gs[g], en = gs[g + 1];
  float sm = 0.f, s2 = 0.f;
#pragma unroll 8
  for (int sl = 0; sl < NSLICE; sl++){
    sm += bnsum[sl*256 + t];
    s2 += bnsum[sl*256 + 128 + t];
  }
  float invn = 1.0f / (float)n;
  float mu = sm * invn;
  float var = s2 * invn - mu*mu;
  float sc = gamma[t] * rsqrtf(var + BN_EPS);
  float sh = beta[t] - mu*sc;
  float s = 0.f;
  for (int r = st; r < en; r++){
    float v = bf2f(h[(size_t)r*D + t]) * sc + sh;
    s += v > 0.f ? v : 0.f;
  }
  float cnt = (float)(en - st);
  sp[t] = s / fmaxf(cnt, 1.0f);
  __syncthreads();
  int wv = t >> 6, m = t & 63;
  for (int k = wv; k < 3; k += 2){
    float acc = hb1[k*64 + m];
    const float* w = hW1 + k*8192 + m;      // [d][m], coalesced over m
#pragma unroll 16
    for (int d = 0; d < 128; d++) acc += sp[d] * w[d*64];
    float val = fmaxf(acc, 0.f) * hW2[k*64 + m];
#pragma unroll
    for (int off = 32; off; off >>= 1) val += __shfl_down(val, off);
    if (m == 0) out[(size_t)g*3 + k] = val + hb2[k];
  }
}

// ---------------- launch ----------------
extern "C" void kernel_launch(void* const* d_in, const int* in_sizes, int n_in,
                              void* d_out, int out_size, void* d_ws, size_t ws_size,
                              hipStream_t stream){
  const float* x    = (const float*)d_in[0];
  const int*   ei   = (const int*)d_in[1];
  const int*   batch= (const int*)d_in[2];
  const float* Wp   = (const float*)d_in[3];
  const float* bp   = (const float*)d_in[4];
  const float* Wg   = (const float*)d_in[5];
  const float* asrc = (const float*)d_in[6];
  const float* adst = (const float*)d_in[7];
  const float* bg   = (const float*)d_in[8];
  const float* gamma= (const float*)d_in[9];
  const float* beta = (const float*)d_in[10];
  const float* hW1  = (const float*)d_in[11];
  const float* hb1  = (const float*)d_in[12];
  const float* hW2  = (const float*)d_in[13];
  const float* hb2  = (const float*)d_in[14];
  float* out = (float*)d_out;

  const int E = in_sizes[1] / 2;
  const int N = in_sizes[2];
  const int G = out_size / 3;
  const int WTOT = in_sizes[5];           // L*D*D
  const int L = WTOT / 16384;

  char* w = (char*)d_ws;
  auto alloc = [&](size_t bytes){ char* p = w; w += (bytes + 255) & ~(size_t)255; return p; };
  ushort* h     = (ushort*)alloc((size_t)N*D*2);
  ushort* xh    = (ushort*)alloc((size_t)N*D*2);
  float* sc2    = (float*)alloc((size_t)N*16*4);
  // zero-initialized region: deg, col, bnsumL contiguous
  int*   deg    = (int*)  alloc((size_t)N*4);
  int*   col    = (int*)  alloc(((size_t)N*MAXDEG + 64)*4);
  float* bnsumL = (float*)alloc((size_t)4*NSLICE*256*4);   // per-layer slices
  char*  zend   = w;
  int*   gs     = (int*)  alloc((size_t)(G + 1)*4);
  ushort* WtB   = (ushort*)alloc((size_t)L*WROWS*D*2);

  hipMemsetAsync(deg, 0, (size_t)(zend - (char*)deg), stream);
  k_scatter<<<(E + 255)/256, 256, 0, stream>>>(ei, deg, col, E);

  const int bInit = (N*32 + 255)/256;
  const int bGb   = (N + 255)/256;
  const int bWp   = (WTOT + 255)/256;
  const int bWsc  = (WTOT/8 + 255)/256;   // L*16*128 elements
  k_setup<<<bInit + bGb + bWp + bWsc, 256, 0, stream>>>(
      x, Wp, bp, h, batch, gs, Wg, asrc, adst, WtB,
      N, G, WTOT, bInit, bGb, bWp);

  for (int l = 0; l < 4; l++){
    float* bnPrev = bnsumL + (size_t)(l - 1)*NSLICE*256;   // unused when l==0
    float* bnCur  = bnsumL + (size_t)l*NSLICE*256;
    k_gemm<<<(N + 255)/256, 512, 0, stream>>>(h, WtB + (size_t)l*WROWS*D, xh, sc2,
                                              l == 0 ? bnCur : bnPrev,
                                              gamma + l*D, beta + l*D, N, l == 0);
    k_agg<<<(N + 15)/16, 512, 0, stream>>>((const uint*)xh, sc2, deg, col,
                                           bg + l*D, h, bnCur, N);
  }

  k_poolheads<<<G, 128, 0, stream>>>(h, gs, bnsumL + (size_t)3*NSLICE*256,
                                     gamma + 3*D, beta + 3*D,
                                     hW1, hb1, hW2, hb2, out, N);
}

// Round 9
// 367.537 us; speedup vs baseline: 1.0851x; 1.0851x over previous
//
#include <hip/hip_runtime.h>

#define D 128
#define NH 8
#define CH 16
#define NEG 0.2f
#define BN_EPS 1e-5f
#define MAXDEG 32
#define NSLICE 32
#define WROWS 144            // 128 weight cols + 16 score cols

typedef unsigned int uint;
typedef unsigned short ushort;
typedef __attribute__((ext_vector_type(8))) short bfrag;
typedef __attribute__((ext_vector_type(4))) float ffrag;

__device__ __forceinline__ float bf_lo(uint u){ return __uint_as_float(u << 16); }
__device__ __forceinline__ float bf_hi(uint u){ return __uint_as_float(u & 0xffff0000u); }
__device__ __forceinline__ float bf2f(ushort s){ return __uint_as_float(((uint)s) << 16); }
__device__ __forceinline__ ushort f2b(float f){
  uint u = __float_as_uint(f);
  u += 0x7fffu + ((u >> 16) & 1u);      // round-to-nearest-even
  return (ushort)(u >> 16);
}

// ---------------- CSR build: row-major slotted scatter (col pre-zeroed) ----------------
__global__ void k_scatter(const int* __restrict__ ei, int* __restrict__ deg,
                          int* __restrict__ col, int E){
  int e = blockIdx.x*blockDim.x + threadIdx.x;
  if (e < E){
    int d = ei[E + e];
    int pos = atomicAdd(&deg[d], 1);
    if (pos < MAXDEG) col[(size_t)d*MAXDEG + pos] = ei[e];
  }
}

// ---------------- fused setup: init(LDS-staged Wp) | gbound | wprep | wsc --------------
__global__ void k_setup(const float* __restrict__ x, const float* __restrict__ Wp,
                        const float* __restrict__ bp, ushort* __restrict__ h,
                        const int* __restrict__ batch, int* __restrict__ gs,
                        const float* __restrict__ Wg, const float* __restrict__ asrc,
                        const float* __restrict__ adst, ushort* __restrict__ WtB,
                        int n, int G, int WTOT, int bInit, int bGb, int bWp){
  int bid = blockIdx.x;
  int t = threadIdx.x;
  if (bid < bInit){
    // Wp staged in LDS once per block (8 KB); inner 64 reads become LDS reads.
    __shared__ float WpL[2048];    // 16 x 128 f32
#pragma unroll
    for (int j = 0; j < 2; j++){
      int u = t + j*256;           // 512 float4 over 256 threads
      ((float4*)WpL)[u] = ((const float4*)Wp)[u];
    }
    __syncthreads();
    int i = bid*256 + t;
    bool valid = i < n*32;
    int nid = i >> 5, d4 = (i & 31)*4;
    if (nid >= n) nid = n - 1;     // safe address for invalid tail threads
    const float* xr = x + (size_t)nid*16;
    float s[4] = { bp[d4], bp[d4+1], bp[d4+2], bp[d4+3] };
#pragma unroll
    for (int k = 0; k < 16; k++){
      float xv = xr[k];            // 32-way broadcast within the nid group
      const float* wr = WpL + k*128 + d4;
      s[0] += xv*wr[0]; s[1] += xv*wr[1]; s[2] += xv*wr[2]; s[3] += xv*wr[3];
    }
    if (valid){
      uint2 o;
      o.x = ((uint)f2b(fmaxf(s[0],0.f))) | (((uint)f2b(fmaxf(s[1],0.f))) << 16);
      o.y = ((uint)f2b(fmaxf(s[2],0.f))) | (((uint)f2b(fmaxf(s[3],0.f))) << 16);
      *(uint2*)(h + (size_t)nid*D + d4) = o;
    }
  } else if (bid < bInit + bGb){
    int i = (bid - bInit)*256 + t;
    if (i >= n) return;
    int b = batch[i];
    int bpv = (i == 0) ? -1 : batch[i-1];
    for (int g = bpv + 1; g <= b; g++) gs[g] = i;
    if (i == n-1) for (int g = b + 1; g <= G; g++) gs[g] = n;
  } else if (bid < bInit + bGb + bWp){
    int i = (bid - bInit - bGb)*256 + t;
    if (i >= WTOT) return;
    int l = i >> 14, r = i & 16383, nn = r >> 7, kk = r & 127;
    WtB[(size_t)l*WROWS*D + nn*D + kk] = f2b(Wg[(size_t)l*16384 + kk*128 + nn]);
  } else {
    int i = (bid - bInit - bGb - bWp)*256 + t;
    int wscTot = (WTOT >> 14)*16*128;     // L*16*128
    if (i >= wscTot) return;
    int l = i >> 11, r = i & 2047, j = r >> 7, k = r & 127;
    const float* wrow = Wg + (size_t)l*16384 + k*128;
    float s = 0.f;
    if (j < 8){
      const float* av = asrc + l*128 + j*16;
#pragma unroll
      for (int c = 0; c < 16; c++) s += wrow[j*16 + c] * av[c];
    } else {
      const float* av = adst + l*128 + (j - 8)*16;
#pragma unroll
      for (int c = 0; c < 16; c++) s += wrow[(j - 8)*16 + c] * av[c];
    }
    WtB[(size_t)l*WROWS*D + (128 + j)*D + k] = f2b(s);
  }
}

// ---------------- MFMA bf16 GEMM 256x144: B staged in LDS once per block ----------------
__global__ __launch_bounds__(512) void k_gemm(const ushort* __restrict__ hin,
                                              const ushort* __restrict__ WtB,
                                              ushort* __restrict__ xh,
                                              float* __restrict__ sc2,
                                              const float* __restrict__ bnsum,
                                              const float* __restrict__ gamma,
                                              const float* __restrict__ beta,
                                              int n, int first){
  __shared__ __align__(16) ushort wL[WROWS*136];   // 144 rows x (128+8 pad) = 39168 B
  __shared__ float sS[128], sB[128];
  int t = threadIdx.x;
  int wid = t >> 6, lane = t & 63, l15 = lane & 15, quad = lane >> 4;
  int n0 = blockIdx.x * 256;
  int rbase = wid*32;                  // wave-private row base (0..224)

  if (t < 128){
    float sc, sh;
    if (first){ sc = 1.f; sh = 0.f; }
    else {
      float s = 0.f, s2 = 0.f;
#pragma unroll 8
      for (int sl = 0; sl < NSLICE; sl++){
        s  += bnsum[sl*256 + t];
        s2 += bnsum[sl*256 + 128 + t];
      }
      float invn = 1.0f / (float)n;
      float mu = s * invn;
      float var = s2 * invn - mu*mu;
      sc = gamma[t] * rsqrtf(var + BN_EPS);
      sh = beta[t] - mu*sc;
    }
    sS[t] = sc; sB[t] = sh;
  }
  // stage B: 144 rows x 16 uint4 = 2304 uint4 over 512 threads
#pragma unroll
  for (int i = 0; i < 5; i++){
    int u = t + i*512;
    if (u < WROWS*16){
      int r = u >> 4, c8 = u & 15;
      *(uint4*)(wL + r*136 + c8*8) = *(const uint4*)(WtB + (size_t)r*D + c8*8);
    }
  }
  __syncthreads();   // the only barrier

  // A fragments: direct global load (16B, aligned), BN+ReLU in registers
  bfrag a[2][4];
#pragma unroll
  for (int mt = 0; mt < 2; mt++){
    int row = n0 + rbase + mt*16 + l15;
#pragma unroll
    for (int ks = 0; ks < 4; ks++){
      union { bfrag b; ushort us[8]; } in, ov;
      in.b = (bfrag){0,0,0,0,0,0,0,0};
      if (row < n) in.b = *(const bfrag*)(hin + (size_t)row*D + ks*32 + quad*8);
      int kb = ks*32 + quad*8;
#pragma unroll
      for (int j = 0; j < 8; j++){
        float f = bf2f(in.us[j])*sS[kb + j] + sB[kb + j];
        ov.us[j] = f2b(f > 0.f ? f : 0.f);
      }
      a[mt][ks] = ov.b;
    }
  }

  ffrag acc[2][9];
#pragma unroll
  for (int mt = 0; mt < 2; mt++)
#pragma unroll
    for (int nt = 0; nt < 9; nt++) acc[mt][nt] = (ffrag){0.f,0.f,0.f,0.f};

  // MFMA with LDS-resident B; nt==8 is the score-column tile
#pragma unroll
  for (int nt = 0; nt < 9; nt++){
#pragma unroll
    for (int ks = 0; ks < 4; ks++){
      bfrag b = *(const bfrag*)(wL + (nt*16 + l15)*136 + ks*32 + quad*8);
      acc[0][nt] = __builtin_amdgcn_mfma_f32_16x16x32_bf16(a[0][ks], b, acc[0][nt], 0, 0, 0);
      acc[1][nt] = __builtin_amdgcn_mfma_f32_16x16x32_bf16(a[1][ks], b, acc[1][nt], 0, 0, 0);
    }
  }

  // epilogue: direct stores, no LDS. C mapping: row = rbase+mt*16+quad*4+r, col = nt*16+l15.
#pragma unroll
  for (int mt = 0; mt < 2; mt++)
#pragma unroll
    for (int r = 0; r < 4; r++){
      int grow = n0 + rbase + mt*16 + quad*4 + r;
      if (grow < n){
        sc2[(size_t)grow*16 + l15] = acc[mt][8][r];
        ushort* xr = xh + (size_t)grow*D + l15;
#pragma unroll
        for (int nt = 0; nt < 8; nt++)
          xr[nt*16] = f2b(acc[mt][nt][r]);
      }
    }
}

// ---------------- wave-per-2-nodes aggregation (R2 measured-best, verbatim) ------------
__global__ __launch_bounds__(512) void k_agg(const uint* __restrict__ xh32,
                                             const float* __restrict__ sc2,
                                             const int* __restrict__ deg,
                                             const int* __restrict__ col,
                                             const float* __restrict__ bg,
                                             ushort* __restrict__ hout,
                                             float* __restrict__ bnsum, int n){
  int wv = threadIdx.x >> 6;
  int l  = threadIdx.x & 63;
  int hs = l & 7;
  int jc = l >> 3;
  int n0 = (blockIdx.x*8 + wv)*2;
  int n1 = n0 + 1;
  bool vA = n0 < n, vB = n1 < n;
  int na = vA ? n0 : 0, nb = vB ? n1 : 0;

  float bnS0=0.f, bnS1=0.f, bnQ0=0.f, bnQ1=0.f;
  float b0 = bg[2*l], b1 = bg[2*l + 1];

  // ---- prefetch phase: everything for chunk 1 of both nodes ----
  int cntA = deg[na]; if (cntA > MAXDEG) cntA = MAXDEG; if (!vA) cntA = 0;
  int cntB = deg[nb]; if (cntB > MAXDEG) cntB = MAXDEG; if (!vB) cntB = 0;
  const int* cbA = col + na*MAXDEG;
  const int* cbB = col + nb*MAXDEG;
  int idxA[8], idxB[8];
#pragma unroll
  for (int j = 0; j < 8; j++){ idxA[j] = cbA[j]; idxB[j] = cbB[j]; }
  int myA = cbA[jc], myB = cbB[jc];          // per-lane slot id
  float asA = sc2[na*16 + hs],     asB = sc2[nb*16 + hs];
  float adA = sc2[na*16 + 8 + hs], adB = sc2[nb*16 + 8 + hs];
  uint selfA = xh32[na*64 + l],    selfB = xh32[nb*64 + l];
  float avA = sc2[myA*16 + hs],    avB = sc2[myB*16 + hs];
  uint gA[8], gB[8];
#pragma unroll
  for (int j = 0; j < 8; j++){ gA[j] = xh32[idxA[j]*64 + l]; gB[j] = xh32[idxB[j]*64 + l]; }

  // ---- interleaved chunk-1 compute ----
  int ccA = cntA < 8 ? cntA : 8;
  int ccB = cntB < 8 ? cntB : 8;
  float e0A = asA + adA; e0A = e0A > 0.f ? e0A : NEG*e0A;
  float e0B = asB + adB; e0B = e0B > 0.f ? e0B : NEG*e0B;
  float mA = e0A, dnmA = 1.f, accA0 = bf_lo(selfA), accA1 = bf_hi(selfA);
  float mB = e0B, dnmB = 1.f, accB0 = bf_lo(selfB), accB1 = bf_hi(selfB);

  float eA = -1e30f, eB = -1e30f;
  if (jc < ccA){ float ee = avA + adA; eA = ee > 0.f ? ee : NEG*ee; }
  if (jc < ccB){ float ee = avB + adB; eB = ee > 0.f ? ee : NEG*ee; }
  float mcA = eA, mcB = eB;
  mcA = fmaxf(mcA, __shfl_xor(mcA, 8));  mcB = fmaxf(mcB, __shfl_xor(mcB, 8));
  mcA = fmaxf(mcA, __shfl_xor(mcA, 16)); mcB = fmaxf(mcB, __shfl_xor(mcB, 16));
  mcA = fmaxf(mcA, __shfl_xor(mcA, 32)); mcB = fmaxf(mcB, __shfl_xor(mcB, 32));
  float mnA = fmaxf(mA, mcA),            mnB = fmaxf(mB, mcB);
  float rscA = __expf(mA - mnA),         rscB = __expf(mB - mnB);
  float wA = (jc < ccA) ? __expf(eA - mnA) : 0.f;
  float wB = (jc < ccB) ? __expf(eB - mnB) : 0.f;
  float wsA = wA, wsB = wB;
  wsA += __shfl_xor(wsA, 8);  wsB += __shfl_xor(wsB, 8);
  wsA += __shfl_xor(wsA, 16); wsB += __shfl_xor(wsB, 16);
  wsA += __shfl_xor(wsA, 32); wsB += __shfl_xor(wsB, 32);
  dnmA = dnmA*rscA + wsA;                dnmB = dnmB*rscB + wsB;
  mA = mnA;                              mB = mnB;
  float rcA = __shfl(rscA, jc),          rcB = __shfl(rscB, jc);
  accA0 *= rcA; accA1 *= rcA;            accB0 *= rcB; accB1 *= rcB;
#pragma unroll
  for (int jj = 0; jj < 8; jj++){
    float wjA = __shfl(wA, jj*8 + jc);
    float wjB = __shfl(wB, jj*8 + jc);
    accA0 += wjA * bf_lo(gA[jj]); accA1 += wjA * bf_hi(gA[jj]);
    accB0 += wjB * bf_lo(gB[jj]); accB1 += wjB * bf_hi(gB[jj]);
  }

  // ---- rare serial remainders (deg > 8), per node ----
  for (int c0 = 8; c0 < cntA; c0 += 8){
    int cc2 = cntA - c0; if (cc2 > 8) cc2 = 8;
    int my2 = cbA[c0 + jc];
    float av2 = sc2[my2*16 + hs];
    uint g2[8];
#pragma unroll
    for (int jj = 0; jj < 8; jj++) g2[jj] = xh32[cbA[c0 + jj]*64 + l];
    float e2 = -1e30f;
    if (jc < cc2){ float ee = av2 + adA; e2 = ee > 0.f ? ee : NEG*ee; }
    float mc2 = e2;
    mc2 = fmaxf(mc2, __shfl_xor(mc2, 8));
    mc2 = fmaxf(mc2, __shfl_xor(mc2, 16));
    mc2 = fmaxf(mc2, __shfl_xor(mc2, 32));
    float mn2 = fmaxf(mA, mc2);
    float rsc2 = __expf(mA - mn2);
    float w2 = (jc < cc2) ? __expf(e2 - mn2) : 0.f;
    float ws2 = w2;
    ws2 += __shfl_xor(ws2, 8);
    ws2 += __shfl_xor(ws2, 16);
    ws2 += __shfl_xor(ws2, 32);
    dnmA = dnmA*rsc2 + ws2; mA = mn2;
    float rc2 = __shfl(rsc2, jc);
    accA0 *= rc2; accA1 *= rc2;
#pragma unroll
    for (int jj = 0; jj < 8; jj++){
      float wj = __shfl(w2, jj*8 + jc);
      accA0 += wj * bf_lo(g2[jj]); accA1 += wj * bf_hi(g2[jj]);
    }
  }
  for (int c0 = 8; c0 < cntB; c0 += 8){
    int cc2 = cntB - c0; if (cc2 > 8) cc2 = 8;
    int my2 = cbB[c0 + jc];
    float av2 = sc2[my2*16 + hs];
    uint g2[8];
#pragma unroll
    for (int jj = 0; jj < 8; jj++) g2[jj] = xh32[cbB[c0 + jj]*64 + l];
    float e2 = -1e30f;
    if (jc < cc2){ float ee = av2 + adB; e2 = ee > 0.f ? ee : NEG*ee; }
    float mc2 = e2;
    mc2 = fmaxf(mc2, __shfl_xor(mc2, 8));
    mc2 = fmaxf(mc2, __shfl_xor(mc2, 16));
    mc2 = fmaxf(mc2, __shfl_xor(mc2, 32));
    float mn2 = fmaxf(mB, mc2);
    float rsc2 = __expf(mB - mn2);
    float w2 = (jc < cc2) ? __expf(e2 - mn2) : 0.f;
    float ws2 = w2;
    ws2 += __shfl_xor(ws2, 8);
    ws2 += __shfl_xor(ws2, 16);
    ws2 += __shfl_xor(ws2, 32);
    dnmB = dnmB*rsc2 + ws2; mB = mn2;
    float rc2 = __shfl(rsc2, jc);
    accB0 *= rc2; accB1 *= rc2;
#pragma unroll
    for (int jj = 0; jj < 8; jj++){
      float wj = __shfl(w2, jj*8 + jc);
      accB0 += wj * bf_lo(g2[jj]); accB1 += wj * bf_hi(g2[jj]);
    }
  }

  // ---- finalize both nodes ----
  float dfA = __shfl(dnmA, jc), dfB = __shfl(dnmB, jc);
  float invA = 1.0f / dfA,      invB = 1.0f / dfB;
  float oA0 = accA0*invA + b0,  oA1 = accA1*invA + b1;
  float oB0 = accB0*invB + b0,  oB1 = accB1*invB + b1;
  if (vA){
    uint p = ((uint)f2b(oA0)) | (((uint)f2b(oA1)) << 16);
    ((uint*)hout)[n0*64 + l] = p;
    bnS0 += oA0; bnS1 += oA1; bnQ0 += oA0*oA0; bnQ1 += oA1*oA1;
  }
  if (vB){
    uint p = ((uint)f2b(oB0)) | (((uint)f2b(oB1)) << 16);
    ((uint*)hout)[n1*64 + l] = p;
    bnS0 += oB0; bnS1 += oB1; bnQ0 += oB0*oB0; bnQ1 += oB1*oB1;
  }

  // ---- block BN reduction ----
  __shared__ float red[8][64][4];
  red[wv][l][0] = bnS0; red[wv][l][1] = bnS1; red[wv][l][2] = bnQ0; red[wv][l][3] = bnQ1;
  __syncthreads();
  if (wv == 0){
    float t0 = 0.f, t1 = 0.f, t2 = 0.f, t3 = 0.f;
#pragma unroll
    for (int k = 0; k < 8; k++){
      t0 += red[k][l][0]; t1 += red[k][l][1];
      t2 += red[k][l][2]; t3 += red[k][l][3];
    }
    float* bs = bnsum + (blockIdx.x & (NSLICE - 1))*256;
    atomicAdd(&bs[2*l],       t0);
    atomicAdd(&bs[2*l + 1],   t1);
    atomicAdd(&bs[128 + 2*l], t2);
    atomicAdd(&bs[129 + 2*l], t3);
  }
}

// ---------------- fused pool (BN+ReLU) + output heads ----------------
__global__ __launch_bounds__(128) void k_poolheads(const ushort* __restrict__ h,
                                                   const int* __restrict__ gs,
                                                   const float* __restrict__ bnsum,
                                                   const float* __restrict__ gamma,
                                                   const float* __restrict__ beta,
                                                   const float* __restrict__ hW1,
                                                   const float* __restrict__ hb1,
                                                   const float* __restrict__ hW2,
                                                   const float* __restrict__ hb2,
                                                   float* __restrict__ out, int n){
  int g = blockIdx.x;
  int t = threadIdx.x;
  __shared__ float sp[128];
  int st = gs[g], en = gs[g + 1];
  float sm = 0.f, s2 = 0.f;
#pragma unroll 8
  for (int sl = 0; sl < NSLICE; sl++){
    sm += bnsum[sl*256 + t];
    s2 += bnsum[sl*256 + 128 + t];
  }
  float invn = 1.0f / (float)n;
  float mu = sm * invn;
  float var = s2 * invn - mu*mu;
  float sc = gamma[t] * rsqrtf(var + BN_EPS);
  float sh = beta[t] - mu*sc;
  float s = 0.f;
  for (int r = st; r < en; r++){
    float v = bf2f(h[(size_t)r*D + t]) * sc + sh;
    s += v > 0.f ? v : 0.f;
  }
  float cnt = (float)(en - st);
  sp[t] = s / fmaxf(cnt, 1.0f);
  __syncthreads();
  int wv = t >> 6, m = t & 63;
  for (int k = wv; k < 3; k += 2){
    float acc = hb1[k*64 + m];
    const float* w = hW1 + k*8192 + m;      // [d][m], coalesced over m
#pragma unroll 16
    for (int d = 0; d < 128; d++) acc += sp[d] * w[d*64];
    float val = fmaxf(acc, 0.f) * hW2[k*64 + m];
#pragma unroll
    for (int off = 32; off; off >>= 1) val += __shfl_down(val, off);
    if (m == 0) out[(size_t)g*3 + k] = val + hb2[k];
  }
}

// ---------------- launch ----------------
extern "C" void kernel_launch(void* const* d_in, const int* in_sizes, int n_in,
                              void* d_out, int out_size, void* d_ws, size_t ws_size,
                              hipStream_t stream){
  const float* x    = (const float*)d_in[0];
  const int*   ei   = (const int*)d_in[1];
  const int*   batch= (const int*)d_in[2];
  const float* Wp   = (const float*)d_in[3];
  const float* bp   = (const float*)d_in[4];
  const float* Wg   = (const float*)d_in[5];
  const float* asrc = (const float*)d_in[6];
  const float* adst = (const float*)d_in[7];
  const float* bg   = (const float*)d_in[8];
  const float* gamma= (const float*)d_in[9];
  const float* beta = (const float*)d_in[10];
  const float* hW1  = (const float*)d_in[11];
  const float* hb1  = (const float*)d_in[12];
  const float* hW2  = (const float*)d_in[13];
  const float* hb2  = (const float*)d_in[14];
  float* out = (float*)d_out;

  const int E = in_sizes[1] / 2;
  const int N = in_sizes[2];
  const int G = out_size / 3;
  const int WTOT = in_sizes[5];           // L*D*D
  const int L = WTOT / 16384;

  char* w = (char*)d_ws;
  auto alloc = [&](size_t bytes){ char* p = w; w += (bytes + 255) & ~(size_t)255; return p; };
  ushort* h     = (ushort*)alloc((size_t)N*D*2);
  ushort* xh    = (ushort*)alloc((size_t)N*D*2);
  float* sc2    = (float*)alloc((size_t)N*16*4);
  // zero-initialized region: deg, col, bnsumL contiguous
  int*   deg    = (int*)  alloc((size_t)N*4);
  int*   col    = (int*)  alloc(((size_t)N*MAXDEG + 64)*4);
  float* bnsumL = (float*)alloc((size_t)4*NSLICE*256*4);   // per-layer slices
  char*  zend   = w;
  int*   gs     = (int*)  alloc((size_t)(G + 1)*4);
  ushort* WtB   = (ushort*)alloc((size_t)L*WROWS*D*2);

  hipMemsetAsync(deg, 0, (size_t)(zend - (char*)deg), stream);
  k_scatter<<<(E + 255)/256, 256, 0, stream>>>(ei, deg, col, E);

  const int bInit = (N*32 + 255)/256;
  const int bGb   = (N + 255)/256;
  const int bWp   = (WTOT + 255)/256;
  const int bWsc  = (WTOT/8 + 255)/256;   // L*16*128 elements
  k_setup<<<bInit + bGb + bWp + bWsc, 256, 0, stream>>>(
      x, Wp, bp, h, batch, gs, Wg, asrc, adst, WtB,
      N, G, WTOT, bInit, bGb, bWp);

  for (int l = 0; l < 4; l++){
    float* bnPrev = bnsumL + (size_t)(l - 1)*NSLICE*256;   // unused when l==0
    float* bnCur  = bnsumL + (size_t)l*NSLICE*256;
    k_gemm<<<(N + 255)/256, 512, 0, stream>>>(h, WtB + (size_t)l*WROWS*D, xh, sc2,
                                              l == 0 ? bnCur : bnPrev,
                                              gamma + l*D, beta + l*D, N, l == 0);
    k_agg<<<(N + 15)/16, 512, 0, stream>>>((const uint*)xh, sc2, deg, col,
                                           bg + l*D, h, bnCur, N);
  }

  k_poolheads<<<G, 128, 0, stream>>>(h, gs, bnsumL + (size_t)3*NSLICE*256,
                                     gamma + 3*D, beta + 3*D,
                                     hW1, hb1, hW2, hb2, out, N);
}